// Round 9
// baseline (218.806 us; speedup 1.0000x reference)
//
#include <hip/hip_runtime.h>

// SNN forward, R8: wave-parallel (lane = neuron), weights VGPR-resident.
//
// spike(h) = (h >= 2.0f)   (h/TAU >= 1 <=> h >= 2, exact in IEEE)
//
// Diagnosis history: thread-per-row structures (R0-R7) all floor at
// 50-83us because each row re-fetches 160 W1 values (don't fit in SGPRs)
// -> per-row scalar-load stalls. R8 transposes: lanes 0-31 = neurons of
// row r0, lanes 32-63 = neurons of row r1. W1 row = 5 VGPRs loaded ONCE.
// x broadcast via ds_bpermute; L1 mask via one __ballot; gmax gate is
// wave-uniform (s_cbranch, no divergence); rare L2/L3/L4 lane-parallel.
// Store: common path writes zeros directly (out is ~all zeros: only
// m2!=0 rows -- O(100) of 2.1M -- are nonzero), so no separate zero-fill.
// Conditional adds in ascending set-bit order are bit-exact vs the
// reference fma chain (absmax 0.0, verified R1-R7).

__global__ __launch_bounds__(256) void snn_wave(
    const float* __restrict__ x,
    const float* __restrict__ W1,   // [32,5]
    const float* __restrict__ W2,   // [32,32]
    const float* __restrict__ W3,   // [16,32]
    const float* __restrict__ W4,   // [10,16]
    float* __restrict__ out,        // [B,10]
    long B)
{
    const int lane   = threadIdx.x & 63;
    const int half   = lane >> 5;        // 0 -> row r0, 1 -> row r1
    const int neuron = lane & 31;

    // ---- W1 row resident in 5 VGPRs (loaded once) ----
    const float w0 = W1[neuron * 5 + 0];
    const float w1 = W1[neuron * 5 + 1];
    const float w2 = W1[neuron * 5 + 2];
    const float w3 = W1[neuron * 5 + 3];
    const float w4 = W1[neuron * 5 + 4];

    // ---- gmax = max positive W2 entry (wave-uniform, once) ----
    float lm = 0.0f;
#pragma unroll
    for (int k = 0; k < 16; ++k) lm = fmaxf(lm, W2[lane + 64 * k]);
#pragma unroll
    for (int k = 1; k < 64; k <<= 1) lm = fmaxf(lm, __shfl_xor(lm, k, 64));
    const float gmax = lm;

    const int xb    = half * 5;                        // x-broadcast src base
    const int svsrc = (lane < 10) ? lane : lane + 22;  // store-gather src lane
    const int j16   = lane & 15;                       // L3/L4 neuron

    const long wid = ((long)blockIdx.x * blockDim.x + threadIdx.x) >> 6;
    const long nw  = ((long)gridDim.x * blockDim.x) >> 6;

    for (long r0 = wid * 2; r0 < B; r0 += nw * 2) {
        // ---- fetch x for rows r0,r0+1: 10 floats at lanes 0..9 ----
        float xv = 0.0f;
        {
            long e = r0 * 5 + lane;
            if (lane < 10 && e < B * 5) xv = x[e];
        }
        const float x0 = __shfl(xv, xb + 0, 64);
        const float x1 = __shfl(xv, xb + 1, 64);
        const float x2 = __shfl(xv, xb + 2, 64);
        const float x3 = __shfl(xv, xb + 3, 64);
        const float x4 = __shfl(xv, xb + 4, 64);

        // ---- layer 1, exact reference op order ----
        float h = x0 * w0;
        h += x1 * w1;
        h += x2 * w2;
        h += x3 * w3;
        h += x4 * w4;

        const unsigned long long ball = __ballot(h >= 2.0f);
        const unsigned mlo = (unsigned)ball;
        const unsigned mhi = (unsigned)(ball >> 32);
        const unsigned m   = half ? mhi : mlo;   // own row's L1 mask

        float oval = 0.0f;

        // gate: h2_j <= popc(m)*gmax*(1+3eps); < 1.99 -> provably no L2 fire
        if (__any((float)__popc(m) * gmax >= 1.99f)) {
            // ---- sparse layer 2, lane-parallel, ascending order (exact) ----
            float h2 = 0.0f;
            unsigned mm = m;
            while (mm) {
                int i = __ffs(mm) - 1;
                mm &= mm - 1;
                h2 += W2[neuron * 32 + i];   // L2-hot gather
            }
            const unsigned long long b2 = __ballot(h2 >= 2.0f);
            if (b2 != 0ull) {                // ultra-rare: O(100) rows total
                const unsigned m2 = half ? (unsigned)(b2 >> 32) : (unsigned)b2;
                // ---- layer 3 at j = lane&15 (lanes 16-31/48-63 dup, masked) ----
                float g = 0.0f;
                unsigned m2m = m2;
                while (m2m) {
                    int i = __ffs(m2m) - 1;
                    m2m &= m2m - 1;
                    g += W3[j16 * 32 + i];
                }
                const unsigned long long b3 = __ballot(g >= 2.0f);
                const unsigned m3 = (half ? (unsigned)(b3 >> 32)
                                          : (unsigned)b3) & 0xFFFFu;
                // ---- layer 4 ----
                float g4 = 0.0f;
                unsigned m3m = m3;
                while (m3m) {
                    int i = __ffs(m3m) - 1;
                    m3m &= m3m - 1;
                    g4 += W4[j16 * 16 + i];
                }
                oval = (g4 >= 2.0f) ? 1.0f : 0.0f;   // valid where j16<10
            }
        }

        // ---- store: lanes 0..19 write out[r0*10 .. r0*10+19] ----
        const float sval = __shfl(oval, svsrc, 64);
        const long eo = r0 * 10 + lane;
        if (lane < 20 && eo < B * 10)
            __builtin_nontemporal_store(sval, &out[eo]);
    }
}

extern "C" void kernel_launch(void* const* d_in, const int* in_sizes, int n_in,
                              void* d_out, int out_size, void* d_ws, size_t ws_size,
                              hipStream_t stream) {
    const float* x  = (const float*)d_in[0];
    const float* W1 = (const float*)d_in[1];
    const float* W2 = (const float*)d_in[2];
    const float* W3 = (const float*)d_in[3];
    const float* W4 = (const float*)d_in[4];
    float* out = (float*)d_out;

    long B = (long)in_sizes[0] / 5;
    snn_wave<<<2048, 256, 0, stream>>>(x, W1, W2, W3, W4, out, B);
}

// Round 10
// 177.819 us; speedup vs baseline: 1.2305x; 1.2305x over previous
//
#include <hip/hip_runtime.h>

// SNN forward, R9: thread-per-row with 8 rows/thread, j-outer weight
// amortization, fused coalesced zero/value stores.
//
// spike(h) = (h >= 2.0f)   (h/TAU >= 1 <=> h >= 2, exact in IEEE)
//
// Diagnosis (R2/R4/R6/R7 counters): all thread-per-row variants floor at
// 50-83us with VALU ~60% idle because the fully-unrolled per-row L1 loop
// re-streams 160 W1 dwords through scalar loads EVERY row (SGPR file can't
// hold them) -> lgkmcnt stall chains. R8 (lane=neuron) fixed weight
// residency but issued 5x more instructions/row and broke write combining
// (NT partial-line stores: WRITE 82->108MB).
//
// R9: j-outer / row-inner over 8 rows per thread: each j's 5 weights are
// loaded once per 8 rows, and the 56-VALU inner body hides the next j's
// s_load latency. Stores: per row 5 plain v2f stores, consecutive lanes =
// consecutive rows -> each wave fully covers 2560B; no NT so L2 combines.
// Gate: h2_j <= popc(m1)*gmax (gmax = max positive W2 entry, wave-reduced
// once) -- popc*gmax < 1.99 provably can't fire layer 2 -> output zeros.
// Rare path (O(100) rows device-wide) exact L2/L3/L4 in ascending set-bit
// order == reference fma-chain order (absmax 0.0 verified R1-R8).

typedef float v2f __attribute__((ext_vector_type(2)));

#define RPT 8   // rows per thread

__global__ __launch_bounds__(256) void snn_fused(
    const float* __restrict__ x,
    const float* __restrict__ W1,   // [32,5]
    const float* __restrict__ W2,   // [32,32]
    const float* __restrict__ W3,   // [16,32]
    const float* __restrict__ W4,   // [10,16]
    float* __restrict__ out,        // [B,10]
    long B)
{
    // ---- gmax = max positive W2 entry (wave-uniform, once per thread-life) ----
    const int lane = threadIdx.x & 63;
    float lm = 0.0f;
#pragma unroll
    for (int k = 0; k < 16; ++k) lm = fmaxf(lm, W2[lane + 64 * k]);
#pragma unroll
    for (int k = 1; k < 64; k <<= 1) lm = fmaxf(lm, __shfl_xor(lm, k, 64));
    const float gmax = lm;

    const long tid = (long)blockIdx.x * 256 + threadIdx.x;
    const long NT  = (long)gridDim.x * 256;   // threads in grid

    for (long base = 0; base < B; base += NT * RPT) {
        // ---- load x for RPT interleaved rows (lanes stay coalesced) ----
        float X[RPT][5];
        long rows[RPT];
#pragma unroll
        for (int i = 0; i < RPT; ++i) {
            long r = base + tid + (long)i * NT;
            rows[i] = r;
            if (r < B) {
                const float* xp = x + r * 5;
                X[i][0] = xp[0]; X[i][1] = xp[1]; X[i][2] = xp[2];
                X[i][3] = xp[3]; X[i][4] = xp[4];
            } else {
                X[i][0] = X[i][1] = X[i][2] = X[i][3] = X[i][4] = 0.0f;
            }
        }

        // ---- layer 1: j-outer (weights amortized over RPT rows) ----
        unsigned msk[RPT];
#pragma unroll
        for (int i = 0; i < RPT; ++i) msk[i] = 0u;

#pragma unroll
        for (int j = 0; j < 32; ++j) {
            const float w0 = W1[j * 5 + 0];
            const float w1 = W1[j * 5 + 1];
            const float w2 = W1[j * 5 + 2];
            const float w3 = W1[j * 5 + 3];
            const float w4 = W1[j * 5 + 4];
#pragma unroll
            for (int i = 0; i < RPT; ++i) {
                float h = X[i][0] * w0;    // exact reference op order
                h += X[i][1] * w1;
                h += X[i][2] * w2;
                h += X[i][3] * w3;
                h += X[i][4] * w4;
                if (h >= 2.0f) msk[i] |= (1u << j);
            }
        }

        // ---- per-row gate + store (zeros common, rare exact path) ----
#pragma unroll
        for (int i = 0; i < RPT; ++i) {
            if (rows[i] >= B) continue;
            float o[10];
#pragma unroll
            for (int j = 0; j < 10; ++j) o[j] = 0.0f;

            const unsigned m = msk[i];
            // h2_j <= popc(m)*gmax*(1+3eps); < 1.99 -> provably no L2 fire
            if ((float)__popc(m) * gmax >= 1.99f) {
                float h[32];
#pragma unroll
                for (int j = 0; j < 32; ++j) h[j] = 0.0f;
                unsigned mm = m;           // ascending set-bit order == ref order
                while (mm) {
                    int ii = __ffs(mm) - 1;
                    mm &= mm - 1;
#pragma unroll
                    for (int j = 0; j < 32; ++j) h[j] += W2[j * 32 + ii];
                }
                unsigned m2 = 0u;
#pragma unroll
                for (int j = 0; j < 32; ++j)
                    if (h[j] >= 2.0f) m2 |= (1u << j);

                if (m2) {   // O(100) rows device-wide: exact layers 3+4
                    unsigned m3 = 0u;
#pragma unroll
                    for (int j = 0; j < 16; ++j) {
                        float g = 0.0f;
#pragma unroll
                        for (int ii = 0; ii < 32; ++ii)
                            if ((m2 >> ii) & 1u) g += W3[j * 32 + ii];
                        if (g >= 2.0f) m3 |= (1u << j);
                    }
#pragma unroll
                    for (int j = 0; j < 10; ++j) {
                        float g = 0.0f;
#pragma unroll
                        for (int ii = 0; ii < 16; ++ii)
                            if ((m3 >> ii) & 1u) g += W4[j * 16 + ii];
                        o[j] = (g >= 2.0f) ? 1.0f : 0.0f;
                    }
                }
            }

            // 5 x v2f stores; consecutive lanes -> full 2560B wave coverage.
            // Plain stores (no NT) so L2 write-combines whole lines.
            v2f* op = (v2f*)(out + rows[i] * 10);   // r*10 even -> 8B aligned
#pragma unroll
            for (int q = 0; q < 5; ++q)
                op[q] = (v2f){ o[2 * q], o[2 * q + 1] };
        }
    }
}

extern "C" void kernel_launch(void* const* d_in, const int* in_sizes, int n_in,
                              void* d_out, int out_size, void* d_ws, size_t ws_size,
                              hipStream_t stream) {
    const float* x  = (const float*)d_in[0];
    const float* W1 = (const float*)d_in[1];
    const float* W2 = (const float*)d_in[2];
    const float* W3 = (const float*)d_in[3];
    const float* W4 = (const float*)d_in[4];
    float* out = (float*)d_out;

    long B = (long)in_sizes[0] / 5;
    // 1024 blocks x 256 thr x 8 rows = 2,097,152 = B exactly (one outer iter)
    snn_fused<<<1024, 256, 0, stream>>>(x, W1, W2, W3, W4, out, B);
}